// Round 5
// baseline (1309.356 us; speedup 1.0000x reference)
//
#include <hip/hip_runtime.h>
#include <stdint.h>

// LSTM_Trend: B=256, T=512, F=64, H=512, P=24.
// Persistent kernel: 256 WGs x 256 threads (1/CU, whole chip) =
// 16 batch-groups (16 rows) x 16 hidden-groups (32 h-units = 128 gate cols).
// Weights register-resident as MFMA B-fragments (144 VGPRs).
//
// R5 = R4's verified XCD-local stores + R1's proven tagged-dword protocol.
// R4 confirmed: batch-groups are XCD-local (rendezvous passes), sc0 stores
// stay dirty in the XCD L2 (WRITE_SIZE 137->2 MB), and sc0sc1 loads hit
// those dirty lines. Remaining cost was protocol structure: 4 dependent L2
// latencies + 4 barriers per step (store, drain, flag, poll, bulk load).
// Tagged dwords -- each h unit stored as (bf16(h)<<16 | t+1) -- fuse data
// and readiness: consumers poll-load the data itself and accept a 16B chunk
// when all 4 embedded tags equal t+1. One L2 visibility latency, 2 barriers,
// no drain/flag/bulk-load. R1 proved this protocol correct (its MALL retry
// flood is gone now that traffic is XCD-local). Skew safety (2 barriers):
// producer stores tag t+3 (overwriting tag t+1 parity) only after its poll
// of tag t+2 succeeded, which requires every peer to have stored t+2, which
// happens after that peer completed its t+1 poll and LDS writes -- so no
// consumer can still need tag-(t+1) data. Tags 1..512 never match 0xAA
// poison or stale parity (t-1), so no workspace memset of the h buffers.
// Fallback (rendezvous popcount!=1): identical protocol with sc0sc1 stores
// (R1-proven correct under any placement, merely slower).

namespace {
constexpr int T_STEPS = 512;
constexpr int FEA  = 64;
constexpr int HID  = 512;
constexpr int KTOT = HID + FEA;   // 576
constexpr int KPAD = KTOT + 8;    // 584 bf16 = 1168 B rows (16B skew)
constexpr int NKI  = KTOT / 32;   // 18 K-iterations
constexpr int GSTR = 132;         // gates LDS row stride (floats)
constexpr int RPG  = 16;          // batch rows per group
constexpr size_t HBUF_DW = 256ull * 512;        // tagged dwords per parity
constexpr size_t GRZ_OFF = 2 * HBUF_DW;         // dword off: gmask[16],gcnt[16]

typedef __bf16   bf16x8 __attribute__((ext_vector_type(8)));
typedef uint16_t u16x8  __attribute__((ext_vector_type(8)));
typedef float    f32x4  __attribute__((ext_vector_type(4)));
typedef uint32_t u32x4  __attribute__((ext_vector_type(4)));
typedef uint32_t u32x2  __attribute__((ext_vector_type(2)));

union V8 { u16x8 u; bf16x8 b; u32x4 q; };

__device__ __forceinline__ float bf2f(uint16_t u) {
  union { uint32_t i; float f; } v; v.i = (uint32_t)u << 16; return v.f;
}
__device__ __forceinline__ uint16_t f2bf(float f) {
  union { float f; uint32_t i; } v; v.f = f;
  uint32_t x = v.i;
  return (uint16_t)((x + 0x7FFFu + ((x >> 16) & 1u)) >> 16);  // RNE
}
__device__ __forceinline__ float sigmoid_f(float x) {
  return 1.0f / (1.0f + __expf(-x));
}
__device__ __forceinline__ float tanh_f(float x) {
  float e = __expf(-2.0f * fabsf(x));
  float t = (1.0f - e) / (1.0f + e);
  return copysignf(t, x);
}
__device__ __forceinline__ bf16x8 load8(const void* base, size_t elem_off,
                                        bool fp32m) {
  V8 r;
  if (fp32m) {
    const float* p = (const float*)base + elem_off;
#pragma unroll
    for (int i = 0; i < 8; ++i) r.u[i] = f2bf(p[i]);
  } else {
    r.q = *(const u32x4*)((const uint16_t*)base + elem_off);
  }
  return r.b;
}
__device__ __forceinline__ float loadf(const void* base, int idx, bool fp32m) {
  return fp32m ? ((const float*)base)[idx] : bf2f(((const uint16_t*)base)[idx]);
}

// ---- exchange memory ops --------------------------------------------------
// Loads: ALWAYS sc0sc1 (L1-bypass; probes the local L2 en route and hits
// dirty lines left by sc0 stores -- proven by R4's passing + WRITE collapse).
__device__ __forceinline__ u32x4 ld128_sc01(const uint32_t* p) {
  u32x4 v;
  asm volatile("global_load_dwordx4 %0, %1, off sc0 sc1"
               : "=v"(v) : "v"(p) : "memory");
  return v;
}
// Stores: sc0 (dirty in XCD L2) on the verified fast path, sc0sc1 on fallback.
__device__ __forceinline__ void st64_x(uint32_t* p, u32x2 v, bool xl) {
  if (xl) asm volatile("global_store_dwordx2 %0, %1, off sc0"
                       :: "v"(p), "v"(v) : "memory");
  else    asm volatile("global_store_dwordx2 %0, %1, off sc0 sc1"
                       :: "v"(p), "v"(v) : "memory");
}
__device__ __forceinline__ void waitcnt_vm0() {
  asm volatile("s_waitcnt vmcnt(0)" ::: "memory");
}
} // namespace

__global__ __launch_bounds__(256, 1) void lstm_persistent(
    const void* __restrict__ x,      // [256][512][64]
    const void* __restrict__ W_ih,   // [2048][64]
    const void* __restrict__ W_hh,   // [2048][512]
    const void* __restrict__ b_ih,   // [2048]
    const void* __restrict__ b_hh,   // [2048]
    const void* __restrict__ W_fc,   // [1536][512]
    const void* __restrict__ b_fc,   // [1536]
    void* __restrict__ out,          // [256][1536]
    uint32_t* __restrict__ dbuf)     // ws: [2][256][512] tagged dwords + rdzv
{
  __shared__ uint16_t Als[RPG * KPAD];   // A tile: [h_{t-1} | x_t], 16 rows
  __shared__ float    Gls[RPG * GSTR];   // gate pre-activations, fp32
  __shared__ int      sflag, sok;

  const int tid = threadIdx.x;
  const int wv  = tid >> 6;              // wave 0..3
  const int ln  = tid & 63;
  const int nl  = ln & 15;               // MFMA m/n lane index
  const int kq  = ln >> 4;               // MFMA k-quad
  const int bg  = blockIdx.x & 15;       // batch group
  const int wgi = blockIdx.x >> 4;       // hidden group 0..15
  const int r0  = bg * RPG;              // first batch row of this group

  // ---- per-group XCD-identity rendezvous (one-time, R4-proven) ------------
  if (tid == 0) {
    uint32_t xcc;
    asm volatile("s_getreg_b32 %0, hwreg(HW_REG_XCC_ID)" : "=s"(xcc));
    unsigned* gmask = (unsigned*)(dbuf + GRZ_OFF) + bg;
    unsigned* gcnt  = (unsigned*)(dbuf + GRZ_OFF) + 16 + bg;
    atomicOr(gmask, 1u << (xcc & 31));
    __threadfence();
    atomicAdd(gcnt, 1u);
    while (atomicAdd(gcnt, 0u) < 16u) __builtin_amdgcn_s_sleep(1);
    __threadfence();
    unsigned m = atomicOr(gmask, 0u);
    sok = (__popc(m) == 1) ? 1 : 0;
  }

  // ---- dtype sniff (block-uniform): fp32 read as bf16 -> huge exponents
  if (tid == 1) sflag = 0;
  __syncthreads();
  {
    float a = fabsf(bf2f(((const uint16_t*)b_ih)[tid]));
    if (a > 1.0f) atomicOr(&sflag, 1);
  }
  __syncthreads();
  const bool fp32m = (sflag != 0);
  const bool xloc  = (sok != 0);

  // wave owns cols [wv*32, wv*32+32) as two 16-col subtiles sharing one A-frag.
  // col mapping: col = 4*unit + gate  (i,f,g,o of one h-unit in 4 adj cols)
  bf16x8 breg[2][NKI];
  float  bias[2];
#pragma unroll
  for (int s = 0; s < 2; ++s) {
    int col  = wv * 32 + s * 16 + nl;    // 0..127
    int gate = col & 3;
    int unit = col >> 2;                 // 0..31
    int gcol = gate * HID + wgi * 32 + unit;
#pragma unroll
    for (int kk = 0; kk < NKI; ++kk) {
      int k0 = kk * 32 + kq * 8;
      if (k0 < HID)
        breg[s][kk] = load8(W_hh, (size_t)gcol * HID + k0, fp32m);
      else
        breg[s][kk] = load8(W_ih, (size_t)gcol * FEA + (k0 - HID), fp32m);
    }
    bias[s] = loadf(b_ih, gcol, fp32m) + loadf(b_hh, gcol, fp32m);
  }

  // activation ownership: row ar (0..15), own units au, au+1 (global hu)
  const int ar  = tid >> 4;
  const int au  = (tid & 15) * 2;
  const int hu  = wgi * 32 + au;
  float c0 = 0.0f, c1 = 0.0f;

  // staging/poll: thread -> row srow, lane-in-row l16.
  // Poll chunks: thread covers dwords {4*l16 + 64*j | j=0..7} of its row
  // (1 tagged dword per h unit). Own WG's 32-unit span is written to LDS
  // directly by the act threads; the (l16,j) chunk inside it is skipped.
  const int srow = tid >> 4;
  const int l16  = tid & 15;
  uint16_t* Ar = &Als[srow * KPAD];
  const uint32_t pend0 =
      ((l16 >> 3) == (wgi & 1)) ? (0xFFu & ~(1u << (wgi >> 1))) : 0xFFu;

  // ---- prologue: h_0 = 0 in LDS, stage x_0 ----
  {
    u32x4 z = {0, 0, 0, 0};
#pragma unroll
    for (int i = 0; i < 4; ++i) *(u32x4*)&Ar[(l16 + 16 * i) * 8] = z;
    int xo = l16 * 4;
    size_t off = (size_t)(r0 + srow) * (T_STEPS * FEA) + xo;
    uint2 w;
    if (fp32m) {
      const float4 xv = *(const float4*)((const float*)x + off);
      w.x = (uint32_t)f2bf(xv.x) | ((uint32_t)f2bf(xv.y) << 16);
      w.y = (uint32_t)f2bf(xv.z) | ((uint32_t)f2bf(xv.w) << 16);
    } else {
      w = *(const uint2*)((const uint16_t*)x + off);
    }
    *(uint2*)&Ar[HID + xo] = w;
  }

  for (int t = 0; t < T_STEPS; ++t) {
    __syncthreads();                     // S1: A tile staged

    // ---- prefetch x_{t+1} into regs (latency hides under MFMA) ----
    const bool havex = (t + 1 < T_STEPS);
    const int xo = l16 * 4;
    float4 xf; uint2 xb;
    if (havex) {
      size_t off = (size_t)(r0 + srow) * (T_STEPS * FEA)
                 + (size_t)(t + 1) * FEA + xo;
      if (fp32m) xf = *(const float4*)((const float*)x + off);
      else       xb = *(const uint2*)((const uint16_t*)x + off);
    }

    // ---- gates = A @ W^T + bias: 18 K-steps, 1 A-frag -> 2 MFMAs ----
    f32x4 acc0, acc1;
    acc0[0] = bias[0]; acc0[1] = bias[0]; acc0[2] = bias[0]; acc0[3] = bias[0];
    acc1[0] = bias[1]; acc1[1] = bias[1]; acc1[2] = bias[1]; acc1[3] = bias[1];
#pragma unroll
    for (int kk = 0; kk < NKI; ++kk) {
      bf16x8 a = *(const bf16x8*)&Als[nl * KPAD + kk * 32 + kq * 8];
      acc0 = __builtin_amdgcn_mfma_f32_16x16x32_bf16(a, breg[0][kk], acc0, 0, 0, 0);
      acc1 = __builtin_amdgcn_mfma_f32_16x16x32_bf16(a, breg[1][kk], acc1, 0, 0, 0);
    }
#pragma unroll
    for (int r = 0; r < 4; ++r) {
      Gls[(kq * 4 + r) * GSTR + wv * 32 + nl]      = acc0[r];
      Gls[(kq * 4 + r) * GSTR + wv * 32 + 16 + nl] = acc1[r];
    }
    __syncthreads();                     // S2: gates ready, Als free

    const uint32_t tg = (uint32_t)(t + 1);

    // ---- activations, cell update; own h -> LDS; tagged store -> L2 ----
    {
      const f32x4* gp = (const f32x4*)&Gls[ar * GSTR + au * 4];
      f32x4 ga = gp[0], gb = gp[1];
      c0 = sigmoid_f(ga[1]) * c0 + sigmoid_f(ga[0]) * tanh_f(ga[2]);
      float h0 = sigmoid_f(ga[3]) * tanh_f(c0);
      c1 = sigmoid_f(gb[1]) * c1 + sigmoid_f(gb[0]) * tanh_f(gb[2]);
      float h1 = sigmoid_f(gb[3]) * tanh_f(c1);
      uint32_t hb0 = f2bf(h0), hb1 = f2bf(h1);
      *(uint32_t*)&Als[ar * KPAD + hu] = hb0 | (hb1 << 16);
      u32x2 w2; w2[0] = (hb0 << 16) | tg; w2[1] = (hb1 << 16) | tg;
      st64_x(dbuf + (size_t)(tg & 1) * HBUF_DW
                  + (size_t)(r0 + ar) * 512 + hu, w2, xloc);
    }

    // ---- x_{t+1} regs -> LDS (x region free after S2) ----
    if (havex) {
      uint2 w;
      if (fp32m) {
        w.x = (uint32_t)f2bf(xf.x) | ((uint32_t)f2bf(xf.y) << 16);
        w.y = (uint32_t)f2bf(xf.z) | ((uint32_t)f2bf(xf.w) << 16);
      } else {
        w = xb;
      }
      *(uint2*)&Ar[HID + xo] = w;
    }

    // ---- poll remote slices: self-validating tagged loads -> LDS ----
    {
      const uint32_t* pr = dbuf + (size_t)(tg & 1) * HBUF_DW
                         + (size_t)(r0 + srow) * 512 + 4 * l16;
      uint32_t pend = pend0;
      u32x4 v[8];
      for (;;) {
#pragma unroll
        for (int j = 0; j < 8; ++j)
          if (pend & (1u << j)) v[j] = ld128_sc01(pr + 64 * j);
        waitcnt_vm0();
#pragma unroll
        for (int j = 0; j < 8; ++j)
          if (pend & (1u << j)) {
            uint32_t m = ((v[j][0] ^ tg) | (v[j][1] ^ tg) |
                          (v[j][2] ^ tg) | (v[j][3] ^ tg)) & 0xFFFFu;
            if (m == 0) {
              uint2 w;
              w.x = (v[j][0] >> 16) | (v[j][1] & 0xFFFF0000u);
              w.y = (v[j][2] >> 16) | (v[j][3] & 0xFFFF0000u);
              *(uint2*)&Ar[4 * l16 + 64 * j] = w;
              pend &= ~(1u << j);
            }
          }
        if (pend == 0) break;
        __builtin_amdgcn_s_sleep(1);
      }
    }
  }
  __syncthreads();                       // h_T fully resident in Als

  // ---- FC head: out = h_T @ W_fc^T + b_fc (A-frags straight from LDS) ----
  int gwave = wgi * 4 + wv;              // 0..63 within the batch group
  for (int tile = gwave; tile < 96; tile += 64) {
    int n = tile * 16 + nl;              // out column
    float bs = loadf(b_fc, n, fp32m);
    f32x4 acc; acc[0] = bs; acc[1] = bs; acc[2] = bs; acc[3] = bs;
#pragma unroll
    for (int kk = 0; kk < 16; ++kk) {
      int k0 = kk * 32 + kq * 8;
      bf16x8 a = *(const bf16x8*)&Als[nl * KPAD + k0];
      bf16x8 b = load8(W_fc, (size_t)n * HID + k0, fp32m);
      acc = __builtin_amdgcn_mfma_f32_16x16x32_bf16(a, b, acc, 0, 0, 0);
    }
#pragma unroll
    for (int r = 0; r < 4; ++r) {
      int row = r0 + kq * 4 + r;
      if (fp32m) ((float*)out)[(size_t)row * 1536 + n] = acc[r];
      else       ((uint16_t*)out)[(size_t)row * 1536 + n] = f2bf(acc[r]);
    }
  }
}

extern "C" void kernel_launch(void* const* d_in, const int* in_sizes, int n_in,
                              void* d_out, int out_size, void* d_ws, size_t ws_size,
                              hipStream_t stream) {
  const void* x    = d_in[0];
  const void* W_ih = d_in[1];
  const void* W_hh = d_in[2];
  const void* b_ih = d_in[3];
  const void* b_hh = d_in[4];
  const void* W_fc = d_in[5];
  const void* b_fc = d_in[6];
  uint32_t* dbuf = (uint32_t*)d_ws;

  // Only the rendezvous scratch (gmask[16], gcnt[16]) needs zeroing; the
  // tagged h buffers self-validate against 0xAA poison / stale parities.
  hipMemsetAsync((void*)(dbuf + GRZ_OFF), 0, 32 * sizeof(uint32_t), stream);

  lstm_persistent<<<dim3(256), dim3(256), 0, stream>>>(
      x, W_ih, W_hh, b_ih, b_hh, W_fc, b_fc, d_out, dbuf);
}